// Round 5
// baseline (788.897 us; speedup 1.0000x reference)
//
#include <hip/hip_runtime.h>
#include <stdint.h>
#include <math.h>

typedef unsigned short u16;
typedef __attribute__((ext_vector_type(8))) short short8;
typedef __attribute__((ext_vector_type(4))) float floatx4;

__device__ __forceinline__ u16 f32_to_bf16(float f) {
    union { float f; uint32_t u; } v; v.f = f;
    uint32_t r = v.u + 0x7FFF + ((v.u >> 16) & 1);   // RTNE
    return (u16)(r >> 16);
}
__device__ __forceinline__ float bf16_to_f32(u16 h) {
    union { uint32_t u; float f; } v; v.u = ((uint32_t)h) << 16; return v.f;
}

__device__ __forceinline__ void gl_lds16(const u16* g, u16* l) {
    __builtin_amdgcn_global_load_lds(
        (const __attribute__((address_space(1))) void*)g,
        (__attribute__((address_space(3))) void*)l, 16, 0, 0);
}

// ---------------- prep (merged: 3 splits + 1 conv in one dispatch) ----------------

__device__ __forceinline__ void split4(const float4& v, ushort4& h, ushort4& l) {
    h.x = f32_to_bf16(v.x); l.x = f32_to_bf16(v.x - bf16_to_f32(h.x));
    h.y = f32_to_bf16(v.y); l.y = f32_to_bf16(v.y - bf16_to_f32(h.y));
    h.z = f32_to_bf16(v.z); l.z = f32_to_bf16(v.z - bf16_to_f32(h.z));
    h.w = f32_to_bf16(v.w); l.w = f32_to_bf16(v.w - bf16_to_f32(h.w));
}

// regions (all multiples of 256 float4s -> block-uniform branches):
// [0,n4X): X -> Xhi/Xlo | [n4X,2n4X): C0 -> C0hi/C0lo | then C1 | then W (hi only)
__global__ void prep_kernel(const float4* __restrict__ X, ushort4* __restrict__ Xhi,
                            ushort4* __restrict__ Xlo,
                            const float4* __restrict__ C0, ushort4* __restrict__ C0hi,
                            ushort4* __restrict__ C0lo,
                            const float4* __restrict__ C1, ushort4* __restrict__ C1hi,
                            ushort4* __restrict__ C1lo,
                            const float4* __restrict__ W, ushort4* __restrict__ Wb,
                            long n4X, long n4C1, long n4W) {
    long i = (long)blockIdx.x * blockDim.x + threadIdx.x;
    if (i < n4X) {
        ushort4 h, l; split4(X[i], h, l); Xhi[i] = h; Xlo[i] = l; return;
    }
    i -= n4X;
    if (i < n4X) {
        ushort4 h, l; split4(C0[i], h, l); C0hi[i] = h; C0lo[i] = l; return;
    }
    i -= n4X;
    if (i < n4C1) {
        ushort4 h, l; split4(C1[i], h, l); C1hi[i] = h; C1lo[i] = l; return;
    }
    i -= n4C1;
    if (i < n4W) {
        float4 v = W[i];
        ushort4 h;
        h.x = f32_to_bf16(v.x); h.y = f32_to_bf16(v.y);
        h.z = f32_to_bf16(v.z); h.w = f32_to_bf16(v.w);
        Wb[i] = h;
    }
}

// bf16 [R][C] -> bf16 [C][R]; pad 34 (68 B = 17 banks, odd -> conflict-free)
__global__ void transpose_u16(const u16* __restrict__ src, u16* __restrict__ dst,
                              int R, int C) {
    __shared__ u16 tile[32][34];
    long base = (long)blockIdx.z * R * C;
    int c0 = blockIdx.x * 32, r0 = blockIdx.y * 32;
    #pragma unroll
    for (int i = threadIdx.y; i < 32; i += 8)
        tile[i][threadIdx.x] = src[base + (long)(r0 + i) * C + c0 + threadIdx.x];
    __syncthreads();
    #pragma unroll
    for (int i = threadIdx.y; i < 32; i += 8)
        dst[base + (long)(c0 + i) * R + r0 + threadIdx.x] = tile[threadIdx.x][i];
}

// in-place row softmax (fp32) + bf16 copy. one wave per row, 4 rows/block.
// merged: blocks [0,nex) do exa (VPT=4), rest do seta (VPT=8).
template <int VPT>
__device__ __forceinline__ void softmax_body(float* __restrict__ data,
                                             u16* __restrict__ outb, int blk) {
    int row = blk * 4 + (threadIdx.x >> 6);
    int lane = threadIdx.x & 63;
    long base = (long)row * (VPT * 64) + lane;
    float v[VPT];
    #pragma unroll
    for (int i = 0; i < VPT; ++i) v[i] = data[base + i * 64];
    float m = v[0];
    #pragma unroll
    for (int i = 1; i < VPT; ++i) m = fmaxf(m, v[i]);
    #pragma unroll
    for (int off = 32; off > 0; off >>= 1) m = fmaxf(m, __shfl_xor(m, off, 64));
    float s = 0.f;
    #pragma unroll
    for (int i = 0; i < VPT; ++i) { v[i] = __expf(v[i] - m); s += v[i]; }
    #pragma unroll
    for (int off = 32; off > 0; off >>= 1) s += __shfl_xor(s, off, 64);
    float inv = 1.0f / s;
    #pragma unroll
    for (int i = 0; i < VPT; ++i) {
        float r = v[i] * inv;
        data[base + i * 64] = r;
        outb[base + i * 64] = f32_to_bf16(r);
    }
}

__global__ void softmax_both(float* __restrict__ exa, u16* __restrict__ exab,
                             float* __restrict__ seta, u16* __restrict__ setab,
                             int nex) {
    int b = blockIdx.x;
    if (b < nex) softmax_body<4>(exa, exab, b);
    else         softmax_body<8>(seta, setab, b - nex);
}

// Shared param struct for the GEMM kernels.
// gemm_bt8 (256x256, 512 thr, 8-phase) and gemm_bt3 (128x128, 256 thr, 3-slot
// counted pipeline) use kshift/kmask/nt. gemm_bt (128x128, 2-barrier) uses nseg/Kper.
struct GemmP {
    const u16* A[3];
    const u16* B[3];
    const u16* B2[3];
    long strideAb, strideBb, strideB2b, strideCb, strideC2b;
    int bdiv, bdiv2, nseg, Kper, kshift, kmask, nt, lda, ldb, ldb2, ldc, ldc2, mode;
    int gx, gy, nx1;
    float* Cf; float* Cf2; u16* Cb; const float* bias;
};

// ---------------- GEMM B: 256x256 tile, 512 thr, 8-phase counted-vmcnt ---------
// EXACT round-1 build (array-indexed seg pointers). Do NOT hoist per-segment
// base pointers out of stA/stB: that edit caused 28 KiB LDS spill
// (LDS_Block_Size 131072 -> 159744) and +110 us. Good-build signature:
// VGPR ~104, LDS_Block_Size 131072.
__global__ __launch_bounds__(512, 2) void gemm_bt8(GemmP p) {
    __shared__ u16 As[32768];   // 4 ring slots x 8192 elems (16 KB) = 64 KB
    __shared__ u16 Bs[32768];
    const int tid  = threadIdx.x;
    const int lane = tid & 63;
    const int wave = tid >> 6;
    const int quad = lane >> 4;
    const int l15  = lane & 15;
    const int wr   = wave >> 2;   // 0..1  (M group, 128 rows)
    const int wc   = wave & 3;    // 0..3  (N group, 64 cols)

    const int f  = blockIdx.x;
    const int Tx = gridDim.x >> 3;
    const int t  = (f & 7) * Tx + (f >> 3);
    const int n  = t % p.gx;
    const int r  = t / p.gx;
    const int m0 = (r % p.gy) * 256;
    const int bz = r / p.gy;

    const u16* Bsegs[3];
    int ldb, ldc, nn, bdv;
    long bstr, cstr;
    float* Cf;
    if (n < p.nx1) {
        Bsegs[0] = p.B[0]; Bsegs[1] = p.B[1]; Bsegs[2] = p.B[2];
        ldb = p.ldb; ldc = p.ldc; bstr = p.strideBb; cstr = p.strideCb;
        Cf = p.Cf; bdv = p.bdiv; nn = n;
    } else {
        Bsegs[0] = p.B2[0]; Bsegs[1] = p.B2[1]; Bsegs[2] = p.B2[2];
        ldb = p.ldb2; ldc = p.ldc2; bstr = p.strideB2b; cstr = p.strideC2b;
        Cf = p.Cf2; bdv = p.bdiv2; nn = n - p.nx1;
    }
    const int n0 = nn * 256;

    const long aoff = (long)bz * p.strideAb + (long)m0 * p.lda;
    const long boff = (long)(bz / bdv) * bstr + (long)n0 * ldb;

    // staging map: thread -> (row = tid>>2 (+128 for 2nd load), 16B chunk = tid&3)
    const int srow = tid >> 2;
    const int sgc  = ((tid & 3) ^ ((srow >> 1) & 3)) * 8;   // pre-swizzled global chunk

    // ds_read per-lane bases (swizzle term invariant under +64/+16 row steps)
    const int rA = wr * 128 + l15;
    const u16* pA = As + rA * 32 + ((quad ^ ((rA >> 1) & 3)) * 8);
    const int rB = wc * 64 + l15;
    const u16* pB = Bs + rB * 32 + ((quad ^ ((rB >> 1) & 3)) * 8);

    const int nt = p.nt;

    auto stA = [&](int kt, int kk) {
        if (kt < nt) {
            const int seg = kt >> p.kshift;
            const u16* g = p.A[seg] + aoff + (long)srow * p.lda
                         + (((kt & p.kmask) << 6) + kk * 32 + sgc);
            u16* d = &As[((((kt & 1) << 1) | kk) << 13) + tid * 8];
            gl_lds16(g, d);
            gl_lds16(g + (long)128 * p.lda, d + 4096);
        }
    };
    auto stB = [&](int kt, int kk) {
        if (kt < nt) {
            const int seg = kt >> p.kshift;
            const u16* g = Bsegs[seg] + boff + (long)srow * ldb
                         + (((kt & p.kmask) << 6) + kk * 32 + sgc);
            u16* d = &Bs[((((kt & 1) << 1) | kk) << 13) + tid * 8];
            gl_lds16(g, d);
            gl_lds16(g + (long)128 * ldb, d + 4096);
        }
    };

    floatx4 acc[8][4];
    #pragma unroll
    for (int i = 0; i < 8; ++i)
        #pragma unroll
        for (int j = 0; j < 4; ++j)
            acc[i][j] = (floatx4){0.f, 0.f, 0.f, 0.f};

    // prologue: tile0 fully + tile1 kk0; vmcnt(4) leaves (1,A0),(1,B0) in flight
    stA(0, 0); stB(0, 0); stA(0, 1); stB(0, 1); stA(1, 0); stB(1, 0);
    asm volatile("s_waitcnt vmcnt(4)" ::: "memory");
    __builtin_amdgcn_s_barrier();

    short8 af[4], bf[4];

#define QPHASE(SO, MH, LOADB, STAGE)                                        \
    {                                                                       \
        _Pragma("unroll")                                                   \
        for (int mi = 0; mi < 4; ++mi)                                      \
            af[mi] = *(const short8*)(pA + (SO) + (MH) * 2048 + mi * 512);  \
        if (LOADB) {                                                        \
            _Pragma("unroll")                                               \
            for (int ni = 0; ni < 4; ++ni)                                  \
                bf[ni] = *(const short8*)(pB + (SO) + ni * 512);            \
        }                                                                   \
        STAGE;                                                              \
        __builtin_amdgcn_s_barrier();                                       \
        asm volatile("s_waitcnt lgkmcnt(0)" ::: "memory");                  \
        __builtin_amdgcn_sched_barrier(0);                                  \
        __builtin_amdgcn_s_setprio(1);                                      \
        _Pragma("unroll")                                                   \
        for (int mi = 0; mi < 4; ++mi)                                      \
            _Pragma("unroll")                                               \
            for (int ni = 0; ni < 4; ++ni)                                  \
                acc[(MH) * 4 + mi][ni] =                                    \
                    __builtin_amdgcn_mfma_f32_16x16x32_bf16(                \
                        af[mi], bf[ni], acc[(MH) * 4 + mi][ni], 0, 0, 0);   \
        __builtin_amdgcn_s_setprio(0);                                      \
        __builtin_amdgcn_sched_barrier(0);                                  \
    }

    for (int kt = 0; kt < nt; ++kt) {
        const int so0 = (kt & 1) << 14;   // slot pair base (elems)
        const int so1 = so0 + 8192;
        QPHASE(so0, 0, true,  stA(kt + 1, 1));
        __builtin_amdgcn_s_barrier();
        QPHASE(so0, 1, false, stB(kt + 1, 1));
        __builtin_amdgcn_s_barrier();
        QPHASE(so1, 0, true,  stA(kt + 2, 0));
        __builtin_amdgcn_s_barrier();
        QPHASE(so1, 1, false, stB(kt + 2, 0));
        if (kt + 2 < nt) {
            asm volatile("s_waitcnt vmcnt(4)" ::: "memory");
        } else {
            asm volatile("s_waitcnt vmcnt(0)" ::: "memory");
        }
        __builtin_amdgcn_s_barrier();
    }
#undef QPHASE

    const long coff = (long)bz * cstr;
    const int rb = m0 + wr * 128 + quad * 4;
    const int cb = n0 + wc * 64 + l15;
    if (p.mode == 2) {
        #pragma unroll
        for (int ni = 0; ni < 4; ++ni) {
            const float bv = p.bias[cb + ni * 16];
            #pragma unroll
            for (int mi = 0; mi < 8; ++mi)
                #pragma unroll
                for (int j = 0; j < 4; ++j)
                    Cf[coff + (long)(rb + mi * 16 + j) * ldc + cb + ni * 16] =
                        tanhf(acc[mi][ni][j] + bv);
        }
    } else if (p.mode == 0) {
        #pragma unroll
        for (int ni = 0; ni < 4; ++ni)
            #pragma unroll
            for (int mi = 0; mi < 8; ++mi)
                #pragma unroll
                for (int j = 0; j < 4; ++j)
                    Cf[coff + (long)(rb + mi * 16 + j) * ldc + cb + ni * 16] =
                        acc[mi][ni][j];
    } else {
        #pragma unroll
        for (int ni = 0; ni < 4; ++ni)
            #pragma unroll
            for (int mi = 0; mi < 8; ++mi)
                #pragma unroll
                for (int j = 0; j < 4; ++j)
                    p.Cb[coff + (long)(rb + mi * 16 + j) * ldc + cb + ni * 16] =
                        f32_to_bf16(acc[mi][ni][j]);
    }
}

// ---------------- GEMM C: 128x128 tile, 256 thr, BK=32, 3-slot counted ring ----
// T3+T4 applied to the 128² kernel: per iter {stage tile t+2 -> slot (t+2)%3;
// ds_read slot t%3; lgkmcnt(0); 16 MFMA; vmcnt(4); barrier}. Loads stay in
// flight across two barriers (counted, never drained mid-loop). 48 KB LDS ->
// 3 blocks/CU. Hazards: W-after-R ok (slot (t+2)%3 = slot (t-1)%3, reads done
// pre-barrier); R-after-W ok (vmcnt(4) at iter t drains exactly tile t+1's 4
// loads; epilogue iters use vmcnt(0)). Numerics = gemm_bt (same summation order).
__global__ __launch_bounds__(256) void gemm_bt3(GemmP p) {
    __shared__ u16 As[3 * 4096];   // 3 slots x [128 rows][32 cols] bf16 (8 KB)
    __shared__ u16 Bs[3 * 4096];
    const int tid  = threadIdx.x;
    const int lane = tid & 63;
    const int wave = tid >> 6;
    const int quad = lane >> 4;
    const int l15  = lane & 15;
    const int wm = (wave & 1) * 64;
    const int wn = (wave >> 1) * 64;

    const int f  = blockIdx.x;
    const int Tx = gridDim.x >> 3;
    const int t  = (f & 7) * Tx + (f >> 3);
    const int n  = t % p.gx;
    const int r  = t / p.gx;
    const int m0 = (r % p.gy) * 128;
    const int bz = r / p.gy;

    const u16* Bsegs[3];
    int ldb, ldc, nn, bdv;
    long bstr, cstr;
    float* Cf;
    if (n < p.nx1) {
        Bsegs[0] = p.B[0]; Bsegs[1] = p.B[1]; Bsegs[2] = p.B[2];
        ldb = p.ldb; ldc = p.ldc; bstr = p.strideBb; cstr = p.strideCb;
        Cf = p.Cf; bdv = p.bdiv; nn = n;
    } else {
        Bsegs[0] = p.B2[0]; Bsegs[1] = p.B2[1]; Bsegs[2] = p.B2[2];
        ldb = p.ldb2; ldc = p.ldc2; bstr = p.strideB2b; cstr = p.strideC2b;
        Cf = p.Cf2; bdv = p.bdiv2; nn = n - p.nx1;
    }
    const int n0 = nn * 128;

    const long aoff = (long)bz * p.strideAb + (long)m0 * p.lda;
    const long boff = (long)(bz / bdv) * bstr + (long)n0 * ldb;

    // staging: row = tid>>2 (0..63; +64 on 2nd call), phys 16B chunk = tid&3.
    // source col pre-swizzled; ((row+64)>>1)&3 == (row>>1)&3 so one sgc serves both.
    const int srow = tid >> 2;
    const int sgc  = ((tid & 3) ^ ((srow >> 1) & 3)) * 8;

    // ds_read bases: row = wm/wn + i*16 + l15; XOR term invariant under +16 steps
    const int rA = wm + l15;
    const int xA = (quad ^ ((rA >> 1) & 3)) * 8;
    const int rB = wn + l15;
    const int xB = (quad ^ ((rB >> 1) & 3)) * 8;

    const int nt = p.nt;

    auto stA = [&](int kt) {
        if (kt < nt) {
            const int seg = kt >> p.kshift;
            const u16* g = p.A[seg] + aoff + (long)srow * p.lda
                         + (((kt & p.kmask) << 5) + sgc);
            u16* d = &As[(kt % 3) * 4096 + tid * 8];
            gl_lds16(g, d);
            gl_lds16(g + (long)64 * p.lda, d + 2048);
        }
    };
    auto stB = [&](int kt) {
        if (kt < nt) {
            const int seg = kt >> p.kshift;
            const u16* g = Bsegs[seg] + boff + (long)srow * ldb
                         + (((kt & p.kmask) << 5) + sgc);
            u16* d = &Bs[(kt % 3) * 4096 + tid * 8];
            gl_lds16(g, d);
            gl_lds16(g + (long)64 * ldb, d + 2048);
        }
    };

    floatx4 acc[4][4];
    #pragma unroll
    for (int i = 0; i < 4; ++i)
        #pragma unroll
        for (int j = 0; j < 4; ++j)
            acc[i][j] = (floatx4){0.f, 0.f, 0.f, 0.f};

    // prologue: tiles 0 and 1 staged; vmcnt(4) -> tile0's 4 loads landed
    stA(0); stB(0); stA(1); stB(1);
    asm volatile("s_waitcnt vmcnt(4)" ::: "memory");
    __builtin_amdgcn_s_barrier();

    for (int kt = 0; kt < nt; ++kt) {
        stA(kt + 2); stB(kt + 2);
        const int so = (kt % 3) * 4096;
        short8 af[4], bfr[4];
        #pragma unroll
        for (int i = 0; i < 4; ++i)
            af[i] = *(const short8*)&As[so + (rA + i * 16) * 32 + xA];
        #pragma unroll
        for (int i = 0; i < 4; ++i)
            bfr[i] = *(const short8*)&Bs[so + (rB + i * 16) * 32 + xB];
        asm volatile("s_waitcnt lgkmcnt(0)" ::: "memory");
        __builtin_amdgcn_sched_barrier(0);
        __builtin_amdgcn_s_setprio(1);
        #pragma unroll
        for (int mi = 0; mi < 4; ++mi)
            #pragma unroll
            for (int ni = 0; ni < 4; ++ni)
                acc[mi][ni] = __builtin_amdgcn_mfma_f32_16x16x32_bf16(
                    af[mi], bfr[ni], acc[mi][ni], 0, 0, 0);
        __builtin_amdgcn_s_setprio(0);
        __builtin_amdgcn_sched_barrier(0);
        if (kt + 2 < nt) {
            asm volatile("s_waitcnt vmcnt(4)" ::: "memory");
        } else {
            asm volatile("s_waitcnt vmcnt(0)" ::: "memory");
        }
        __builtin_amdgcn_s_barrier();
    }

    const long coff = (long)bz * cstr;
    const int rb = m0 + wm + quad * 4;
    const int cbase = n0 + wn + l15;
    if (p.mode == 2) {
        #pragma unroll
        for (int ni = 0; ni < 4; ++ni) {
            const float bv = p.bias[cbase + ni * 16];
            #pragma unroll
            for (int mi = 0; mi < 4; ++mi)
                #pragma unroll
                for (int j = 0; j < 4; ++j)
                    Cf[coff + (long)(rb + mi * 16 + j) * ldc + cbase + ni * 16] =
                        tanhf(acc[mi][ni][j] + bv);
        }
    } else if (p.mode == 0) {
        #pragma unroll
        for (int ni = 0; ni < 4; ++ni)
            #pragma unroll
            for (int mi = 0; mi < 4; ++mi)
                #pragma unroll
                for (int j = 0; j < 4; ++j)
                    Cf[coff + (long)(rb + mi * 16 + j) * ldc + cbase + ni * 16] =
                        acc[mi][ni][j];
    } else {
        #pragma unroll
        for (int ni = 0; ni < 4; ++ni)
            #pragma unroll
            for (int mi = 0; mi < 4; ++mi)
                #pragma unroll
                for (int j = 0; j < 4; ++j)
                    p.Cb[coff + (long)(rb + mi * 16 + j) * ldc + cbase + ni * 16] =
                        f32_to_bf16(acc[mi][ni][j]);
    }
}

// ---------------- host ----------------
extern "C" void kernel_launch(void* const* d_in, const int* in_sizes, int n_in,
                              void* d_out, int out_size, void* d_ws, size_t ws_size,
                              hipStream_t stream) {
    const int BT = 80, L = 256, S = 512, H = 1024;
    const long NO    = (long)BT * L * H;   // 20971520
    const long NC1   = (long)8 * S * H;    // 4194304
    const long NW    = (long)H * 3 * H;    // 3145728
    const long NEXA  = (long)BT * L * L;   // 5242880
    const long NSETA = (long)BT * L * S;   // 10485760

    const float* X    = (const float*)d_in[0];
    const float* C0   = (const float*)d_in[1];
    const float* C1   = (const float*)d_in[2];
    const float* Wf   = (const float*)d_in[4];
    const float* bias = (const float*)d_in[5];

    float* out  = (float*)d_out;
    float* exa  = out + NO;
    float* seta = exa + NEXA;

    char* wsb = (char*)d_ws;
    size_t off = 0;
    auto alloc = [&](long nbytes) -> void* {
        void* p = (void*)(wsb + off);
        off += ((size_t)nbytes + 255) & ~(size_t)255;
        return p;
    };
    u16* Xhi  = (u16*)alloc(NO * 2);
    u16* Xlo  = (u16*)alloc(NO * 2);
    u16* C0hi = (u16*)alloc(NO * 2);
    u16* C0lo = (u16*)alloc(NO * 2);
    u16* C1hi = (u16*)alloc(NC1 * 2);
    u16* C1lo = (u16*)alloc(NC1 * 2);
    u16* Wb   = (u16*)alloc(NW * 2);
    u16* exab = (u16*)alloc(NEXA * 2);
    u16* setab= (u16*)alloc(NSETA * 2);
    // aliases (lifetimes disjoint by launch order):
    u16* C0T = C0lo;   // written by transpose after G12 (C0lo read in G12 part1 seg2)
    u16* C1T = C1lo;   // written by transpose after G12 (C1lo read in G12 part2 seg2)
    u16* exc = Xlo;    // written by GEMM3 (Xlo last read in G12)
    u16* setc = C0hi;  // written by GEMM4 (C0hi last read by transpose #1)

    // --- prep (single dispatch) ---
    {
        const long n4X = NO / 4, n4C1 = NC1 / 4, n4W = NW / 4;
        const long tot = 2 * n4X + n4C1 + n4W;   // 12320768, multiple of 256
        prep_kernel<<<(int)(tot / 256), 256, 0, stream>>>(
            (const float4*)X, (ushort4*)Xhi, (ushort4*)Xlo,
            (const float4*)C0, (ushort4*)C0hi, (ushort4*)C0lo,
            (const float4*)C1, (ushort4*)C1hi, (ushort4*)C1lo,
            (const float4*)Wf, (ushort4*)Wb, n4X, n4C1, n4W);
    }

    // --- merged GEMM1+2 (8-phase 256², R1 config): logits = X @ [C0 | set_ctx]^T
    {
        GemmP p{};
        p.A[0] = Xhi;  p.A[1] = Xlo;  p.A[2] = Xhi;
        p.B[0]  = C0hi; p.B[1]  = C0hi; p.B[2]  = C0lo;
        p.B2[0] = C1hi; p.B2[1] = C1hi; p.B2[2] = C1lo;
        p.strideAb = (long)L * H;
        p.strideBb = (long)L * H;  p.strideB2b = (long)S * H;
        p.strideCb = (long)L * L;  p.strideC2b = (long)L * S;
        p.bdiv = 1; p.bdiv2 = 10;
        p.kshift = 4; p.kmask = 15; p.nt = 48;   // 3 segs x (1024/64)
        p.lda = H; p.ldb = H; p.ldb2 = H;
        p.ldc = L; p.ldc2 = S; p.mode = 0;
        p.gx = 3; p.gy = 1; p.nx1 = 1;
        p.Cf = exa; p.Cf2 = seta;
        gemm_bt8<<<dim3(3 * 1 * BT, 1, 1), 512, 0, stream>>>(p);
    }
    softmax_both<<<2 * (BT * L / 4), 256, 0, stream>>>(exa, exab, seta, setab, BT * L / 4);

    // --- transposes for PV B-operands ---
    transpose_u16<<<dim3(H / 32, L / 32, BT), dim3(32, 8), 0, stream>>>(C0hi, C0T, L, H);
    transpose_u16<<<dim3(H / 32, S / 32, 8), dim3(32, 8), 0, stream>>>(C1hi, C1T, S, H);

    // --- GEMM3: ex_c = ex_attn @ C0 -> bf16 exc (8-phase, R1 config) ---
    {
        GemmP p{};
        p.A[0] = exab; p.B[0] = C0T;
        p.strideAb = (long)L * L; p.strideBb = (long)H * L; p.strideCb = (long)L * H;
        p.bdiv = 1; p.kshift = 2; p.kmask = 3; p.nt = 4;   // K=256
        p.lda = L; p.ldb = L; p.ldc = H; p.mode = 1;
        p.gx = 4; p.gy = 1; p.nx1 = 4;
        p.Cb = exc;
        gemm_bt8<<<dim3(4 * 1 * BT, 1, 1), 512, 0, stream>>>(p);
    }
    // --- GEMM4: set_c = set_attn @ set_ctx -> bf16 setc (8-phase, R1 config) ---
    {
        GemmP p{};
        p.A[0] = setab; p.B[0] = C1T;
        p.strideAb = (long)L * S; p.strideBb = (long)H * S; p.strideCb = (long)L * H;
        p.bdiv = 10; p.kshift = 3; p.kmask = 7; p.nt = 8;  // K=512
        p.lda = S; p.ldb = S; p.ldc = H; p.mode = 1;
        p.gx = 4; p.gy = 1; p.nx1 = 4;
        p.Cb = setc;
        gemm_bt8<<<dim3(4 * 1 * BT, 1, 1), 512, 0, stream>>>(p);
    }
    // --- GEMM5: out = tanh(concat(X, ex_c, set_c) @ W^T + b), M = 20480
    //     (3-slot counted-pipeline kernel; was gemm_bt @ 220us) ---
    {
        GemmP p{};
        p.A[0] = Xhi; p.A[1] = exc; p.A[2] = setc;
        p.B[0] = Wb;  p.B[1] = Wb + 1024; p.B[2] = Wb + 2048;
        p.strideAb = 0; p.strideBb = 0; p.strideCb = 0;
        p.bdiv = 1; p.kshift = 5; p.kmask = 31; p.nt = 96;  // 3 segs x (1024/32)
        p.lda = H; p.ldb = 3 * H; p.ldc = H; p.mode = 2;
        p.gx = 8; p.gy = BT * L / 128; p.nx1 = 8;
        p.Cf = out; p.bias = bias;
        gemm_bt3<<<dim3(8 * (BT * L / 128), 1, 1), 256, 0, stream>>>(p);
    }
}

// Round 6
// 740.073 us; speedup vs baseline: 1.0660x; 1.0660x over previous
//
#include <hip/hip_runtime.h>
#include <stdint.h>
#include <math.h>

typedef unsigned short u16;
typedef __attribute__((ext_vector_type(8))) short short8;
typedef __attribute__((ext_vector_type(4))) float floatx4;

__device__ __forceinline__ u16 f32_to_bf16(float f) {
    union { float f; uint32_t u; } v; v.f = f;
    uint32_t r = v.u + 0x7FFF + ((v.u >> 16) & 1);   // RTNE
    return (u16)(r >> 16);
}
__device__ __forceinline__ float bf16_to_f32(u16 h) {
    union { uint32_t u; float f; } v; v.u = ((uint32_t)h) << 16; return v.f;
}

__device__ __forceinline__ void gl_lds16(const u16* g, u16* l) {
    __builtin_amdgcn_global_load_lds(
        (const __attribute__((address_space(1))) void*)g,
        (__attribute__((address_space(3))) void*)l, 16, 0, 0);
}

// ---------------- prep (merged: 3 splits + 1 conv in one dispatch) ----------------

__device__ __forceinline__ void split4(const float4& v, ushort4& h, ushort4& l) {
    h.x = f32_to_bf16(v.x); l.x = f32_to_bf16(v.x - bf16_to_f32(h.x));
    h.y = f32_to_bf16(v.y); l.y = f32_to_bf16(v.y - bf16_to_f32(h.y));
    h.z = f32_to_bf16(v.z); l.z = f32_to_bf16(v.z - bf16_to_f32(h.z));
    h.w = f32_to_bf16(v.w); l.w = f32_to_bf16(v.w - bf16_to_f32(h.w));
}

// regions (all multiples of 256 float4s -> block-uniform branches):
// [0,n4X): X -> Xhi/Xlo | [n4X,2n4X): C0 -> C0hi/C0lo | then C1 | then W (hi only)
__global__ void prep_kernel(const float4* __restrict__ X, ushort4* __restrict__ Xhi,
                            ushort4* __restrict__ Xlo,
                            const float4* __restrict__ C0, ushort4* __restrict__ C0hi,
                            ushort4* __restrict__ C0lo,
                            const float4* __restrict__ C1, ushort4* __restrict__ C1hi,
                            ushort4* __restrict__ C1lo,
                            const float4* __restrict__ W, ushort4* __restrict__ Wb,
                            long n4X, long n4C1, long n4W) {
    long i = (long)blockIdx.x * blockDim.x + threadIdx.x;
    if (i < n4X) {
        ushort4 h, l; split4(X[i], h, l); Xhi[i] = h; Xlo[i] = l; return;
    }
    i -= n4X;
    if (i < n4X) {
        ushort4 h, l; split4(C0[i], h, l); C0hi[i] = h; C0lo[i] = l; return;
    }
    i -= n4X;
    if (i < n4C1) {
        ushort4 h, l; split4(C1[i], h, l); C1hi[i] = h; C1lo[i] = l; return;
    }
    i -= n4C1;
    if (i < n4W) {
        float4 v = W[i];
        ushort4 h;
        h.x = f32_to_bf16(v.x); h.y = f32_to_bf16(v.y);
        h.z = f32_to_bf16(v.z); h.w = f32_to_bf16(v.w);
        Wb[i] = h;
    }
}

// merged transposes: bf16 [R][C] -> [C][R] for C0hi (R=256, 80 batches) and
// C1hi (R=512, 8 batches), one 1-D dispatch. pad 34 -> conflict-free.
__global__ void transpose_both(const u16* __restrict__ srcA, u16* __restrict__ dstA,
                               const u16* __restrict__ srcB, u16* __restrict__ dstB,
                               int nA /* = 20480 */) {
    __shared__ u16 tile[32][34];
    int b = blockIdx.x;
    const u16* src; u16* dst; int R, x, y, z;
    if (b < nA) {
        src = srcA; dst = dstA; R = 256;
        x = b & 31; y = (b >> 5) & 7; z = b >> 8;
    } else {
        b -= nA;
        src = srcB; dst = dstB; R = 512;
        x = b & 31; y = (b >> 5) & 15; z = b >> 9;
    }
    const int C = 1024;
    long base = (long)z * R * C;
    int c0 = x * 32, r0 = y * 32;
    #pragma unroll
    for (int i = threadIdx.y; i < 32; i += 8)
        tile[i][threadIdx.x] = src[base + (long)(r0 + i) * C + c0 + threadIdx.x];
    __syncthreads();
    #pragma unroll
    for (int i = threadIdx.y; i < 32; i += 8)
        dst[base + (long)(c0 + i) * R + r0 + threadIdx.x] = tile[threadIdx.x][i];
}

// in-place row softmax (fp32) + bf16 copy. one wave per row, 4 rows/block.
// merged: blocks [0,nex) do exa (VPT=4), rest do seta (VPT=8).
template <int VPT>
__device__ __forceinline__ void softmax_body(float* __restrict__ data,
                                             u16* __restrict__ outb, int blk) {
    int row = blk * 4 + (threadIdx.x >> 6);
    int lane = threadIdx.x & 63;
    long base = (long)row * (VPT * 64) + lane;
    float v[VPT];
    #pragma unroll
    for (int i = 0; i < VPT; ++i) v[i] = data[base + i * 64];
    float m = v[0];
    #pragma unroll
    for (int i = 1; i < VPT; ++i) m = fmaxf(m, v[i]);
    #pragma unroll
    for (int off = 32; off > 0; off >>= 1) m = fmaxf(m, __shfl_xor(m, off, 64));
    float s = 0.f;
    #pragma unroll
    for (int i = 0; i < VPT; ++i) { v[i] = __expf(v[i] - m); s += v[i]; }
    #pragma unroll
    for (int off = 32; off > 0; off >>= 1) s += __shfl_xor(s, off, 64);
    float inv = 1.0f / s;
    #pragma unroll
    for (int i = 0; i < VPT; ++i) {
        float r = v[i] * inv;
        data[base + i * 64] = r;
        outb[base + i * 64] = f32_to_bf16(r);
    }
}

__global__ void softmax_both(float* __restrict__ exa, u16* __restrict__ exab,
                             float* __restrict__ seta, u16* __restrict__ setab,
                             int nex) {
    int b = blockIdx.x;
    if (b < nex) softmax_body<4>(exa, exab, b);
    else         softmax_body<8>(seta, setab, b - nex);
}

// Shared param struct for the GEMM kernels.
// gemm_bt8 (256x256, 512 thr, 8-phase) uses kshift/kmask/nt.
// gemm_bt  (128x128, 256 thr, 2-barrier) uses nseg/Kper.
struct GemmP {
    const u16* A[3];
    const u16* B[3];
    const u16* B2[3];
    long strideAb, strideBb, strideB2b, strideCb, strideC2b;
    int bdiv, bdiv2, nseg, Kper, kshift, kmask, nt, lda, ldb, ldb2, ldc, ldc2, mode;
    int gx, gy, nx1;
    float* Cf; float* Cf2; u16* Cb; const float* bias;
};

// ---------------- GEMM B: 256x256 tile, 512 thr, 8-phase counted-vmcnt ---------
// EXACT round-1 build (array-indexed seg pointers). Do NOT hoist per-segment
// base pointers out of stA/stB: that edit caused 28 KiB LDS spill
// (LDS_Block_Size 131072 -> 159744) and +110 us. Good-build signature:
// VGPR ~104, LDS_Block_Size 131072.
// Deployment (per-dispatch measured): G12/G3/G4 yes; G5 no (262 vs bt's 220 —
// 320-block tail at 1 blk/CU).
__global__ __launch_bounds__(512, 2) void gemm_bt8(GemmP p) {
    __shared__ u16 As[32768];   // 4 ring slots x 8192 elems (16 KB) = 64 KB
    __shared__ u16 Bs[32768];
    const int tid  = threadIdx.x;
    const int lane = tid & 63;
    const int wave = tid >> 6;
    const int quad = lane >> 4;
    const int l15  = lane & 15;
    const int wr   = wave >> 2;   // 0..1  (M group, 128 rows)
    const int wc   = wave & 3;    // 0..3  (N group, 64 cols)

    const int f  = blockIdx.x;
    const int Tx = gridDim.x >> 3;
    const int t  = (f & 7) * Tx + (f >> 3);
    const int n  = t % p.gx;
    const int r  = t / p.gx;
    const int m0 = (r % p.gy) * 256;
    const int bz = r / p.gy;

    const u16* Bsegs[3];
    int ldb, ldc, nn, bdv;
    long bstr, cstr;
    float* Cf;
    if (n < p.nx1) {
        Bsegs[0] = p.B[0]; Bsegs[1] = p.B[1]; Bsegs[2] = p.B[2];
        ldb = p.ldb; ldc = p.ldc; bstr = p.strideBb; cstr = p.strideCb;
        Cf = p.Cf; bdv = p.bdiv; nn = n;
    } else {
        Bsegs[0] = p.B2[0]; Bsegs[1] = p.B2[1]; Bsegs[2] = p.B2[2];
        ldb = p.ldb2; ldc = p.ldc2; bstr = p.strideB2b; cstr = p.strideC2b;
        Cf = p.Cf2; bdv = p.bdiv2; nn = n - p.nx1;
    }
    const int n0 = nn * 256;

    const long aoff = (long)bz * p.strideAb + (long)m0 * p.lda;
    const long boff = (long)(bz / bdv) * bstr + (long)n0 * ldb;

    // staging map: thread -> (row = tid>>2 (+128 for 2nd load), 16B chunk = tid&3)
    const int srow = tid >> 2;
    const int sgc  = ((tid & 3) ^ ((srow >> 1) & 3)) * 8;   // pre-swizzled global chunk

    // ds_read per-lane bases (swizzle term invariant under +64/+16 row steps)
    const int rA = wr * 128 + l15;
    const u16* pA = As + rA * 32 + ((quad ^ ((rA >> 1) & 3)) * 8);
    const int rB = wc * 64 + l15;
    const u16* pB = Bs + rB * 32 + ((quad ^ ((rB >> 1) & 3)) * 8);

    const int nt = p.nt;

    auto stA = [&](int kt, int kk) {
        if (kt < nt) {
            const int seg = kt >> p.kshift;
            const u16* g = p.A[seg] + aoff + (long)srow * p.lda
                         + (((kt & p.kmask) << 6) + kk * 32 + sgc);
            u16* d = &As[((((kt & 1) << 1) | kk) << 13) + tid * 8];
            gl_lds16(g, d);
            gl_lds16(g + (long)128 * p.lda, d + 4096);
        }
    };
    auto stB = [&](int kt, int kk) {
        if (kt < nt) {
            const int seg = kt >> p.kshift;
            const u16* g = Bsegs[seg] + boff + (long)srow * ldb
                         + (((kt & p.kmask) << 6) + kk * 32 + sgc);
            u16* d = &Bs[((((kt & 1) << 1) | kk) << 13) + tid * 8];
            gl_lds16(g, d);
            gl_lds16(g + (long)128 * ldb, d + 4096);
        }
    };

    floatx4 acc[8][4];
    #pragma unroll
    for (int i = 0; i < 8; ++i)
        #pragma unroll
        for (int j = 0; j < 4; ++j)
            acc[i][j] = (floatx4){0.f, 0.f, 0.f, 0.f};

    // prologue: tile0 fully + tile1 kk0; vmcnt(4) leaves (1,A0),(1,B0) in flight
    stA(0, 0); stB(0, 0); stA(0, 1); stB(0, 1); stA(1, 0); stB(1, 0);
    asm volatile("s_waitcnt vmcnt(4)" ::: "memory");
    __builtin_amdgcn_s_barrier();

    short8 af[4], bf[4];

#define QPHASE(SO, MH, LOADB, STAGE)                                        \
    {                                                                       \
        _Pragma("unroll")                                                   \
        for (int mi = 0; mi < 4; ++mi)                                      \
            af[mi] = *(const short8*)(pA + (SO) + (MH) * 2048 + mi * 512);  \
        if (LOADB) {                                                        \
            _Pragma("unroll")                                               \
            for (int ni = 0; ni < 4; ++ni)                                  \
                bf[ni] = *(const short8*)(pB + (SO) + ni * 512);            \
        }                                                                   \
        STAGE;                                                              \
        __builtin_amdgcn_s_barrier();                                       \
        asm volatile("s_waitcnt lgkmcnt(0)" ::: "memory");                  \
        __builtin_amdgcn_sched_barrier(0);                                  \
        __builtin_amdgcn_s_setprio(1);                                      \
        _Pragma("unroll")                                                   \
        for (int mi = 0; mi < 4; ++mi)                                      \
            _Pragma("unroll")                                               \
            for (int ni = 0; ni < 4; ++ni)                                  \
                acc[(MH) * 4 + mi][ni] =                                    \
                    __builtin_amdgcn_mfma_f32_16x16x32_bf16(                \
                        af[mi], bf[ni], acc[(MH) * 4 + mi][ni], 0, 0, 0);   \
        __builtin_amdgcn_s_setprio(0);                                      \
        __builtin_amdgcn_sched_barrier(0);                                  \
    }

    for (int kt = 0; kt < nt; ++kt) {
        const int so0 = (kt & 1) << 14;   // slot pair base (elems)
        const int so1 = so0 + 8192;
        QPHASE(so0, 0, true,  stA(kt + 1, 1));
        __builtin_amdgcn_s_barrier();
        QPHASE(so0, 1, false, stB(kt + 1, 1));
        __builtin_amdgcn_s_barrier();
        QPHASE(so1, 0, true,  stA(kt + 2, 0));
        __builtin_amdgcn_s_barrier();
        QPHASE(so1, 1, false, stB(kt + 2, 0));
        if (kt + 2 < nt) {
            asm volatile("s_waitcnt vmcnt(4)" ::: "memory");
        } else {
            asm volatile("s_waitcnt vmcnt(0)" ::: "memory");
        }
        __builtin_amdgcn_s_barrier();
    }
#undef QPHASE

    const long coff = (long)bz * cstr;
    const int rb = m0 + wr * 128 + quad * 4;
    const int cb = n0 + wc * 64 + l15;
    if (p.mode == 2) {
        #pragma unroll
        for (int ni = 0; ni < 4; ++ni) {
            const float bv = p.bias[cb + ni * 16];
            #pragma unroll
            for (int mi = 0; mi < 8; ++mi)
                #pragma unroll
                for (int j = 0; j < 4; ++j)
                    Cf[coff + (long)(rb + mi * 16 + j) * ldc + cb + ni * 16] =
                        tanhf(acc[mi][ni][j] + bv);
        }
    } else if (p.mode == 0) {
        #pragma unroll
        for (int ni = 0; ni < 4; ++ni)
            #pragma unroll
            for (int mi = 0; mi < 8; ++mi)
                #pragma unroll
                for (int j = 0; j < 4; ++j)
                    Cf[coff + (long)(rb + mi * 16 + j) * ldc + cb + ni * 16] =
                        acc[mi][ni][j];
    } else {
        #pragma unroll
        for (int ni = 0; ni < 4; ++ni)
            #pragma unroll
            for (int mi = 0; mi < 8; ++mi)
                #pragma unroll
                for (int j = 0; j < 4; ++j)
                    p.Cb[coff + (long)(rb + mi * 16 + j) * ldc + cb + ni * 16] =
                        f32_to_bf16(acc[mi][ni][j]);
    }
}

// ---------------- GEMM A: 128x128 tile, 256 thr, 2-barrier loop (m97-class) ----
// G5 champion @ 220us. Falsified alternatives for G5: bt8 8-phase 256² (262us,
// 320-blk tail @ 1 blk/CU), bt3 3-slot BK=32 counted ring (273us — forced
// lgkmcnt(0)+sched_barrier drain before each 16-MFMA cluster defeats the
// compiler's fine-grained lgkmcnt interleave; prefetch depth too shallow).
// mode 0: fp32 | mode 1: bf16 | mode 2: fp32 tanh(acc+bias[col])
__global__ __launch_bounds__(256) void gemm_bt(GemmP p) {
    __shared__ u16 As[128 * 64];
    __shared__ u16 Bs[128 * 64];
    const int tid  = threadIdx.x;
    const int lane = tid & 63;
    const int wave = tid >> 6;
    const int quad = lane >> 4;
    const int l15  = lane & 15;
    const int wm = (wave & 1) * 64;
    const int wn = (wave >> 1) * 64;

    const int f  = blockIdx.x;
    const int Tx = gridDim.x >> 3;
    const int t  = (f & 7) * Tx + (f >> 3);
    const int n  = t % p.gx;
    const int r  = t / p.gx;
    const int m0 = (r % p.gy) * 128;
    const int bz = r / p.gy;

    const u16* Bsegs[3];
    int ldb, ldc, nn, bdv;
    long bstr, cstr;
    float* Cf;
    if (n < p.nx1) {
        Bsegs[0] = p.B[0]; Bsegs[1] = p.B[1]; Bsegs[2] = p.B[2];
        ldb = p.ldb; ldc = p.ldc; bstr = p.strideBb; cstr = p.strideCb;
        Cf = p.Cf; bdv = p.bdiv; nn = n;
    } else {
        Bsegs[0] = p.B2[0]; Bsegs[1] = p.B2[1]; Bsegs[2] = p.B2[2];
        ldb = p.ldb2; ldc = p.ldc2; bstr = p.strideB2b; cstr = p.strideC2b;
        Cf = p.Cf2; bdv = p.bdiv2; nn = n - p.nx1;
    }
    const int n0 = nn * 128;

    const int stg_r8 = tid >> 3;
    const int stg_c  = ((tid & 7) ^ (stg_r8 & 7)) * 8;
    const int xorl   = l15 & 7;

    floatx4 acc[4][4];
    #pragma unroll
    for (int i = 0; i < 4; ++i)
        #pragma unroll
        for (int j = 0; j < 4; ++j)
            acc[i][j] = (floatx4){0.f, 0.f, 0.f, 0.f};

    const long aoff = (long)bz * p.strideAb + (long)m0 * p.lda;
    const long boff = (long)(bz / bdv) * bstr + (long)n0 * ldb;

    for (int seg = 0; seg < p.nseg; ++seg) {
        const u16* Ag = p.A[seg] + aoff;
        const u16* Bg = Bsegs[seg] + boff;
        for (int k0 = 0; k0 < p.Kper; k0 += 64) {
            __syncthreads();
            #pragma unroll
            for (int i = 0; i < 4; ++i) {
                const int rr = i * 32 + stg_r8;
                gl_lds16(Ag + (long)rr * p.lda + k0 + stg_c, &As[(i * 256 + tid) * 8]);
            }
            #pragma unroll
            for (int i = 0; i < 4; ++i) {
                const int rr = i * 32 + stg_r8;
                gl_lds16(Bg + (long)rr * ldb + k0 + stg_c, &Bs[(i * 256 + tid) * 8]);
            }
            __syncthreads();
            #pragma unroll
            for (int kk = 0; kk < 2; ++kk) {
                const int cs = ((kk * 4 + quad) ^ xorl) * 8;
                short8 af[4], bfr[4];
                #pragma unroll
                for (int i = 0; i < 4; ++i)
                    af[i] = *(const short8*)&As[(wm + i * 16 + l15) * 64 + cs];
                #pragma unroll
                for (int i = 0; i < 4; ++i)
                    bfr[i] = *(const short8*)&Bs[(wn + i * 16 + l15) * 64 + cs];
                #pragma unroll
                for (int mi = 0; mi < 4; ++mi)
                    #pragma unroll
                    for (int ni = 0; ni < 4; ++ni)
                        acc[mi][ni] = __builtin_amdgcn_mfma_f32_16x16x32_bf16(
                            af[mi], bfr[ni], acc[mi][ni], 0, 0, 0);
            }
        }
    }

    const long coff = (long)bz * cstr;
    const int rb = m0 + wm + quad * 4;
    const int cbase = n0 + wn + l15;
    if (p.mode == 2) {
        #pragma unroll
        for (int ni = 0; ni < 4; ++ni) {
            const float bv = p.bias[cbase + ni * 16];
            #pragma unroll
            for (int mi = 0; mi < 4; ++mi)
                #pragma unroll
                for (int j = 0; j < 4; ++j)
                    Cf[coff + (long)(rb + mi * 16 + j) * ldc + cbase + ni * 16] =
                        tanhf(acc[mi][ni][j] + bv);
        }
    } else if (p.mode == 0) {
        #pragma unroll
        for (int ni = 0; ni < 4; ++ni)
            #pragma unroll
            for (int mi = 0; mi < 4; ++mi)
                #pragma unroll
                for (int j = 0; j < 4; ++j)
                    Cf[coff + (long)(rb + mi * 16 + j) * ldc + cbase + ni * 16] =
                        acc[mi][ni][j];
    } else {
        #pragma unroll
        for (int ni = 0; ni < 4; ++ni)
            #pragma unroll
            for (int mi = 0; mi < 4; ++mi)
                #pragma unroll
                for (int j = 0; j < 4; ++j)
                    p.Cb[coff + (long)(rb + mi * 16 + j) * ldc + cbase + ni * 16] =
                        f32_to_bf16(acc[mi][ni][j]);
    }
}

// ---------------- host ----------------
extern "C" void kernel_launch(void* const* d_in, const int* in_sizes, int n_in,
                              void* d_out, int out_size, void* d_ws, size_t ws_size,
                              hipStream_t stream) {
    const int BT = 80, L = 256, S = 512, H = 1024;
    const long NO    = (long)BT * L * H;   // 20971520
    const long NC1   = (long)8 * S * H;    // 4194304
    const long NW    = (long)H * 3 * H;    // 3145728
    const long NEXA  = (long)BT * L * L;   // 5242880
    const long NSETA = (long)BT * L * S;   // 10485760

    const float* X    = (const float*)d_in[0];
    const float* C0   = (const float*)d_in[1];
    const float* C1   = (const float*)d_in[2];
    const float* Wf   = (const float*)d_in[4];
    const float* bias = (const float*)d_in[5];

    float* out  = (float*)d_out;
    float* exa  = out + NO;
    float* seta = exa + NEXA;

    char* wsb = (char*)d_ws;
    size_t off = 0;
    auto alloc = [&](long nbytes) -> void* {
        void* p = (void*)(wsb + off);
        off += ((size_t)nbytes + 255) & ~(size_t)255;
        return p;
    };
    u16* Xhi  = (u16*)alloc(NO * 2);
    u16* Xlo  = (u16*)alloc(NO * 2);
    u16* C0hi = (u16*)alloc(NO * 2);
    u16* C0lo = (u16*)alloc(NO * 2);
    u16* C1hi = (u16*)alloc(NC1 * 2);
    u16* C1lo = (u16*)alloc(NC1 * 2);
    u16* Wb   = (u16*)alloc(NW * 2);
    u16* exab = (u16*)alloc(NEXA * 2);
    u16* setab= (u16*)alloc(NSETA * 2);
    // aliases (lifetimes disjoint by launch order):
    u16* C0T = C0lo;   // written by transpose after G12 (C0lo read in G12 part1 seg2)
    u16* C1T = C1lo;   // written by transpose after G12 (C1lo read in G12 part2 seg2)
    u16* exc = Xlo;    // written by GEMM3 (Xlo last read in G12)
    u16* setc = C0hi;  // written by GEMM4 (C0hi last read by transpose)

    // --- prep (single dispatch) ---
    {
        const long n4X = NO / 4, n4C1 = NC1 / 4, n4W = NW / 4;
        const long tot = 2 * n4X + n4C1 + n4W;   // multiple of 256
        prep_kernel<<<(int)(tot / 256), 256, 0, stream>>>(
            (const float4*)X, (ushort4*)Xhi, (ushort4*)Xlo,
            (const float4*)C0, (ushort4*)C0hi, (ushort4*)C0lo,
            (const float4*)C1, (ushort4*)C1hi, (ushort4*)C1lo,
            (const float4*)Wf, (ushort4*)Wb, n4X, n4C1, n4W);
    }

    // --- merged GEMM1+2 (8-phase 256², R1 config): logits = X @ [C0 | set_ctx]^T
    {
        GemmP p{};
        p.A[0] = Xhi;  p.A[1] = Xlo;  p.A[2] = Xhi;
        p.B[0]  = C0hi; p.B[1]  = C0hi; p.B[2]  = C0lo;
        p.B2[0] = C1hi; p.B2[1] = C1hi; p.B2[2] = C1lo;
        p.strideAb = (long)L * H;
        p.strideBb = (long)L * H;  p.strideB2b = (long)S * H;
        p.strideCb = (long)L * L;  p.strideC2b = (long)L * S;
        p.bdiv = 1; p.bdiv2 = 10;
        p.kshift = 4; p.kmask = 15; p.nt = 48;   // 3 segs x (1024/64)
        p.lda = H; p.ldb = H; p.ldb2 = H;
        p.ldc = L; p.ldc2 = S; p.mode = 0;
        p.gx = 3; p.gy = 1; p.nx1 = 1;
        p.Cf = exa; p.Cf2 = seta;
        gemm_bt8<<<dim3(3 * 1 * BT, 1, 1), 512, 0, stream>>>(p);
    }
    softmax_both<<<2 * (BT * L / 4), 256, 0, stream>>>(exa, exab, seta, setab, BT * L / 4);

    // --- transposes for PV B-operands (merged: 20480 C0 blocks + 4096 C1 blocks) ---
    transpose_both<<<20480 + 4096, dim3(32, 8), 0, stream>>>(C0hi, C0T, C1hi, C1T, 20480);

    // --- GEMM3: ex_c = ex_attn @ C0 -> bf16 exc (8-phase, R1 config) ---
    {
        GemmP p{};
        p.A[0] = exab; p.B[0] = C0T;
        p.strideAb = (long)L * L; p.strideBb = (long)H * L; p.strideCb = (long)L * H;
        p.bdiv = 1; p.kshift = 2; p.kmask = 3; p.nt = 4;   // K=256
        p.lda = L; p.ldb = L; p.ldc = H; p.mode = 1;
        p.gx = 4; p.gy = 1; p.nx1 = 4;
        p.Cb = exc;
        gemm_bt8<<<dim3(4 * 1 * BT, 1, 1), 512, 0, stream>>>(p);
    }
    // --- GEMM4: set_c = set_attn @ set_ctx -> bf16 setc (8-phase, R1 config) ---
    {
        GemmP p{};
        p.A[0] = setab; p.B[0] = C1T;
        p.strideAb = (long)L * S; p.strideBb = (long)H * S; p.strideCb = (long)L * H;
        p.bdiv = 10; p.kshift = 3; p.kmask = 7; p.nt = 8;  // K=512
        p.lda = S; p.ldb = S; p.ldc = H; p.mode = 1;
        p.gx = 4; p.gy = 1; p.nx1 = 4;
        p.Cb = setc;
        gemm_bt8<<<dim3(4 * 1 * BT, 1, 1), 512, 0, stream>>>(p);
    }
    // --- GEMM5: out = tanh(concat(X, ex_c, set_c) @ W^T + b), M = 20480
    //     (gemm_bt, R0 config — measured champion @ 220us) ---
    {
        GemmP p{};
        p.A[0] = Xhi; p.A[1] = exc; p.A[2] = setc;
        p.B[0] = Wb;  p.B[1] = Wb + 1024; p.B[2] = Wb + 2048;
        p.strideAb = 0; p.strideBb = 0; p.strideCb = 0;
        p.bdiv = 1; p.nseg = 3; p.Kper = H; p.lda = H; p.ldb = 3 * H; p.ldc = H; p.mode = 2;
        p.gx = 8; p.gy = BT * L / 128; p.nx1 = 8;
        p.Cf = out; p.bias = bias;
        gemm_bt<<<dim3(8 * (BT * L / 128), 1, 1), 256, 0, stream>>>(p);
    }
}